// Round 9
// baseline (97.053 us; speedup 1.0000x reference)
//
#include <hip/hip_runtime.h>

// PointWarping2: Nadaraya-Watson regression of flow1 (at warped sources
// y = xyz1+flow1) onto queries xyz2. B=2,C=3,N1=N2=8192 fp32.
//
// R9: pure-scalar inner loop (CDNA4 fp32 peak = 1 FMA/lane/cyc; v_pk_f32
// saves issue slots only -> dropped). Schraudolph exp2 with the magic
// constant folded into the packed source term at pack time:
//   ya.w = MAGIC - c1*|y|^2;  s = max(dot-chain + ya.w, MAGIC-120)
//   w = bitcast<float>((bitcast<int>(s) << 15) + KBITS)   (+-3.04% rel err)
// -> 10 VALU ops per (query,source) pair. 1024 blocks x 256 thr; block owns
// QB=16 queries (wave-uniform consts via readfirstlane -> SGPRs), 4 waves =
// 4 source chunks of 2048 streamed from L2 with 2-deep prefetch. 64-float
// accumulator reduced by the R8-proven split-exchange butterfly (63 shfl).

#define N1S  8192
#define N2S  8192
#define BATCH 2
#define NS   (BATCH * N1S)     // 16384 sources
#define NQ   (BATCH * N2S)     // 16384 queries
#define BLK  256               // 4 waves
#define QB   16                // queries per block (shared by all 4 waves)
#define CHUNK 2048             // sources per wave
#define ITERS (CHUNK / 64)     // 32
#define LOG2E 1.4426950408889634f
#define MAGIC 49152.0f         // 1.5*2^15
#define CLAMPS (MAGIC - 120.0f)
#define KBITS 1064990910       // (127<<23) - 362306: centers rel err +-3.04%

__device__ __forceinline__ float rfl(float x) {   // force wave-uniform -> SGPR
    return __builtin_bit_cast(float,
        __builtin_amdgcn_readfirstlane(__builtin_bit_cast(int, x)));
}

__device__ __forceinline__ float read_scale(const void* p) {
    // resol_factor: 1-elem array; Python int -> int32, float -> fp32.
    int iv = *(const int*)p;
    if (iv > -(1 << 23) && iv < (1 << 23)) return (float)iv;
    return *(const float*)p;
}

// ---- k1: ya[i]={yx,yy,yz, MAGIC-c1|y|^2}, fv[i]={fx,fy,fz,0} ----
__global__ __launch_bounds__(256) void pw2_pack(
    const float* __restrict__ xyz1, const float* __restrict__ flow1,
    const void* __restrict__ resol, float4* __restrict__ ya,
    float4* __restrict__ fv)
{
    int i = blockIdx.x * 256 + threadIdx.x;
    if (i >= NS) return;
    int b = i >> 13, m = i & (N1S - 1);
    const float scale = read_scale(resol);
    const float c1 = LOG2E / (scale * scale);
    const float* x1b = xyz1  + b * 3 * N1S;
    const float* f1b = flow1 + b * 3 * N1S;
    float fx = f1b[0*N1S+m], fy = f1b[1*N1S+m], fz = f1b[2*N1S+m];
    float yx = x1b[0*N1S+m]+fx, yy = x1b[1*N1S+m]+fy, yz = x1b[2*N1S+m]+fz;
    float yc = MAGIC - c1 * (yx*yx + yy*yy + yz*yz);
    ya[i] = make_float4(yx, yy, yz, yc);
    fv[i] = make_float4(fx, fy, fz, 0.f);
}

// ---- k2: main streaming kernel ----
__global__ __launch_bounds__(BLK) void pw2_main(
    const float4* __restrict__ ya, const float4* __restrict__ fv,
    const float* __restrict__ xyz2, const void* __restrict__ resol,
    float* __restrict__ out)
{
    __shared__ float red[4 * 64];      // [wave][flat idx = c*16 + q]

    const int t = threadIdx.x;
    const int w = t >> 6;              // wave = source chunk
    const int l = t & 63;

    const int qblk  = blockIdx.x * QB;
    const int b     = qblk >> 13;
    const int nbase = qblk & (N2S - 1);

    const float scale = read_scale(resol);   // INITIAL_RADIUS == 1.0
    const float c1    = LOG2E / (scale * scale);
    const float twoC  = 2.0f * c1;

    const float* x2b = xyz2 + b * 3 * N2S;

    // ---- wave-uniform query constants (16 queries) -> SGPRs ----
    float qx[QB], qy[QB], qz[QB], qc[QB];
#pragma unroll
    for (int q = 0; q < QB; ++q) {
        int n = nbase + q;
        float x = x2b[0*N2S+n], y = x2b[1*N2S+n], z = x2b[2*N2S+n];
        qc[q] = rfl(-c1 * (x*x + y*y + z*z));
        qx[q] = rfl(twoC*x); qy[q] = rfl(twoC*y); qz[q] = rfl(twoC*z);
    }

    // v[c*16+q]: c=0/1/2 numerator xyz, c=3 denominator
    float v[64];
#pragma unroll
    for (int i = 0; i < 64; ++i) v[i] = 0.f;

#define BODY(Y4, F4) do {                                                     \
    _Pragma("unroll")                                                         \
    for (int q = 0; q < QB; ++q) {                                            \
        float arg = fmaf(qz[q], (Y4).z,                                       \
                    fmaf(qy[q], (Y4).y,                                       \
                    fmaf(qx[q], (Y4).x, qc[q])));                             \
        float s = fmaxf(arg + (Y4).w, CLAMPS);     /* magic-domain clamp */   \
        float wgt = __builtin_bit_cast(float,                                 \
            (__builtin_bit_cast(int, s) << 15) + KBITS);                      \
        v[0*16+q] = fmaf(wgt, (F4).x, v[0*16+q]);                             \
        v[1*16+q] = fmaf(wgt, (F4).y, v[1*16+q]);                             \
        v[2*16+q] = fmaf(wgt, (F4).z, v[2*16+q]);                             \
        v[3*16+q] += wgt;                                                     \
    }                                                                         \
} while (0)

    // ---- stream 2048 sources from L2, 2-deep (pairwise) prefetch ----
    int idx = b * N1S + w * CHUNK + l;
    float4 yA = ya[idx],      fA = fv[idx];
    float4 yB = ya[idx + 64], fB = fv[idx + 64];
    for (int it = 0; it < ITERS; it += 2) {
        const int nidx = (it + 2 < ITERS) ? idx + 128 : idx;
        float4 yC = ya[nidx],      fC = fv[nidx];
        float4 yD = ya[nidx + 64], fD = fv[nidx + 64];
        BODY(yA, fA);
        BODY(yB, fB);
        yA = yC; fA = fC; yB = yD; fB = fD;
        idx = nidx;
    }
#undef BODY

    // ---- split-exchange butterfly: 64 values x 64 lanes -> 1/lane ----
#pragma unroll
    for (int step = 0; step < 6; ++step) {
        const int off  = 1 << step;
        const int half = 32 >> step;
        const bool hi  = (l & off) != 0;
#pragma unroll
        for (int k = 0; k < half; ++k) {
            float give = hi ? v[k] : v[k + half];
            float recv = __shfl_xor(give, off, 64);
            float keep = hi ? v[k + half] : v[k];
            v[k] = keep + recv;
        }
    }
    red[w * 64 + (__brev((unsigned)l) >> 26)] = v[0];
    __syncthreads();

    // ---- combine 4 chunk partials per query, normalize, write ----
    if (t < QB) {
        int q = t;
        float nx = 0.f, ny = 0.f, nz = 0.f, dn = 0.f;
#pragma unroll
        for (int ww = 0; ww < 4; ++ww) {
            nx += red[ww * 64 + 0 * 16 + q];
            ny += red[ww * 64 + 1 * 16 + q];
            nz += red[ww * 64 + 2 * 16 + q];
            dn += red[ww * 64 + 3 * 16 + q];
        }
        float inv = 1.0f / dn;
        int n = nbase + q;
        out[b*3*N2S + 0*N2S + n] = x2b[0*N2S+n] - nx*inv;
        out[b*3*N2S + 1*N2S + n] = x2b[1*N2S+n] - ny*inv;
        out[b*3*N2S + 2*N2S + n] = x2b[2*N2S+n] - nz*inv;
    }
}

extern "C" void kernel_launch(void* const* d_in, const int* in_sizes, int n_in,
                              void* d_out, int out_size, void* d_ws, size_t ws_size,
                              hipStream_t stream) {
    const float* xyz1  = (const float*)d_in[0];
    const float* xyz2  = (const float*)d_in[1];
    const float* flow1 = (const float*)d_in[2];
    const void*  resol = d_in[3];
    float* out = (float*)d_out;

    float4* ya = (float4*)d_ws;            // NS float4 = 256 KB
    float4* fv = ya + NS;                  // NS float4 = 256 KB

    pw2_pack<<<NS / 256, 256, 0, stream>>>(xyz1, flow1, resol, ya, fv);
    pw2_main<<<NQ / QB, BLK, 0, stream>>>(ya, fv, xyz2, resol, out);
}

// Round 10
// 91.824 us; speedup vs baseline: 1.0569x; 1.0569x over previous
//
#include <hip/hip_runtime.h>

// PointWarping2: Nadaraya-Watson regression of flow1 (at warped sources
// y = xyz1+flow1) onto queries xyz2. B=2,C=3,N1=N2=8192 fp32.
//
// R10 = all verified wins combined:
//  * f2 packed fp32 (v_pk_*_f32 measured full-rate: 2 cyc/wave64 -> 2x FLOPs;
//    R6/R7 busy-time fits, R8>R9 confirms)
//  * Schraudolph exp2, magic folded into packed yc (R9: absmax 0.0156)
//  * QT=8 queries/wave -> 32 accum floats: fits the allocator's ~64-VGPR
//    comfort zone (R9's 64 accums -> AGPR blits, 1.7x busy inflation)
//  * flow packed bf16 (uint2, 8B) + y fp32x4 (16B) = 24B/source ->
//    L2 traffic 384 MB, floor ~10.4 us
// 2048 blocks x 256 thr; block owns QB=8 queries (wave-uniform consts in
// SGPRs via readfirstlane); 4 waves = 4 source chunks of 2048, 2-deep
// prefetch from L2; 32-value split-exchange butterfly + xor-32 finish.

#define N1S  8192
#define N2S  8192
#define BATCH 2
#define NS   (BATCH * N1S)     // 16384 sources
#define NQ   (BATCH * N2S)     // 16384 queries
#define BLK  256               // 4 waves
#define QB   8                 // queries per block (shared by all 4 waves)
#define QP   4                 // f2 query-pairs per wave
#define CHUNK 2048             // sources per wave
#define ITERS (CHUNK / 64)     // 32
#define LOG2E 1.4426950408889634f
#define MAGIC 49152.0f         // 1.5*2^15
#define CLAMPS (MAGIC - 120.0f)
#define KBITS 1064990910       // (127<<23) - 362306: rel err +-3.04%

typedef float f2 __attribute__((ext_vector_type(2)));

__device__ __forceinline__ f2 fma2(f2 a, f2 b, f2 c) {
    return __builtin_elementwise_fma(a, b, c);
}
__device__ __forceinline__ f2 max2(f2 a, f2 b) {
    return __builtin_elementwise_max(a, b);
}

__device__ __forceinline__ float rfl(float x) {   // force wave-uniform -> SGPR
    return __builtin_bit_cast(float,
        __builtin_amdgcn_readfirstlane(__builtin_bit_cast(int, x)));
}

__device__ __forceinline__ float read_scale(const void* p) {
    // resol_factor: 1-elem array; Python int -> int32, float -> fp32.
    int iv = *(const int*)p;
    if (iv > -(1 << 23) && iv < (1 << 23)) return (float)iv;
    return *(const float*)p;
}

__device__ __forceinline__ unsigned bf16_rne(float v) {   // round-nearest-even
    unsigned u = __builtin_bit_cast(unsigned, v);
    return (u + 0x7FFFu + ((u >> 16) & 1u)) >> 16;
}

// ---- k1: ya[i]={yx,yy,yz, MAGIC-c1|y|^2}, fb[i]={bf16 fy:fx, bf16 0:fz} ----
__global__ __launch_bounds__(256) void pw2_pack(
    const float* __restrict__ xyz1, const float* __restrict__ flow1,
    const void* __restrict__ resol, float4* __restrict__ ya,
    uint2* __restrict__ fb)
{
    int i = blockIdx.x * 256 + threadIdx.x;
    if (i >= NS) return;
    int b = i >> 13, m = i & (N1S - 1);
    const float scale = read_scale(resol);
    const float c1 = LOG2E / (scale * scale);
    const float* x1b = xyz1  + b * 3 * N1S;
    const float* f1b = flow1 + b * 3 * N1S;
    float fx = f1b[0*N1S+m], fy = f1b[1*N1S+m], fz = f1b[2*N1S+m];
    float yx = x1b[0*N1S+m]+fx, yy = x1b[1*N1S+m]+fy, yz = x1b[2*N1S+m]+fz;
    float yc = MAGIC - c1 * (yx*yx + yy*yy + yz*yz);
    ya[i] = make_float4(yx, yy, yz, yc);
    fb[i] = make_uint2((bf16_rne(fy) << 16) | bf16_rne(fx), bf16_rne(fz));
}

// ---- k2: main streaming kernel ----
__global__ __launch_bounds__(BLK) void pw2_main(
    const float4* __restrict__ ya, const uint2* __restrict__ fb,
    const float* __restrict__ xyz2, const void* __restrict__ resol,
    float* __restrict__ out)
{
    __shared__ float red[4 * 32];      // [wave][32 reduced values]

    const int t = threadIdx.x;
    const int w = t >> 6;              // wave = source chunk
    const int l = t & 63;

    const int qblk  = blockIdx.x * QB;
    const int b     = qblk >> 13;
    const int nbase = qblk & (N2S - 1);

    const float scale = read_scale(resol);   // INITIAL_RADIUS == 1.0
    const float c1    = LOG2E / (scale * scale);
    const float twoC  = 2.0f * c1;

    const float* x2b = xyz2 + b * 3 * N2S;

    // ---- wave-uniform query constants (8 queries, f2 pairs) -> SGPRs ----
    f2 qx[QP], qy[QP], qz[QP], qc[QP];
#pragma unroll
    for (int jp = 0; jp < QP; ++jp) {
        int n0 = nbase + 2 * jp;
        float x0 = x2b[0*N2S+n0],   y0 = x2b[1*N2S+n0],   z0 = x2b[2*N2S+n0];
        float x1 = x2b[0*N2S+n0+1], y1 = x2b[1*N2S+n0+1], z1 = x2b[2*N2S+n0+1];
        qc[jp] = (f2){rfl(-c1 * (x0*x0 + y0*y0 + z0*z0)),
                      rfl(-c1 * (x1*x1 + y1*y1 + z1*z1))};
        qx[jp] = (f2){rfl(twoC*x0), rfl(twoC*x1)};
        qy[jp] = (f2){rfl(twoC*y0), rfl(twoC*y1)};
        qz[jp] = (f2){rfl(twoC*z0), rfl(twoC*z1)};
    }
    const f2 clamp2 = (f2){CLAMPS, CLAMPS};

    // acc.v2[c*QP+jp]: c=0/1/2 numerator xyz, c=3 denominator; 32 floats
    union Acc { f2 v2[16]; float v1[32]; } acc;
#pragma unroll
    for (int i = 0; i < 16; ++i) acc.v2[i] = (f2){0.f, 0.f};

#define BODY(Y4, FU) do {                                                     \
    f2 yaw = (f2){(Y4).w, (Y4).w};                                            \
    f2 yax = (f2){(Y4).x, (Y4).x};                                            \
    f2 yay = (f2){(Y4).y, (Y4).y};                                            \
    f2 yaz = (f2){(Y4).z, (Y4).z};                                            \
    float ffx = __builtin_bit_cast(float, (FU).x << 16);                      \
    float ffy = __builtin_bit_cast(float, (FU).x & 0xFFFF0000u);              \
    float ffz = __builtin_bit_cast(float, (FU).y << 16);                      \
    f2 fax = (f2){ffx, ffx}, fay = (f2){ffy, ffy}, faz = (f2){ffz, ffz};      \
    _Pragma("unroll")                                                         \
    for (int jp = 0; jp < QP; ++jp) {                                         \
        f2 arg = qc[jp] + yaw;                                                \
        arg = fma2(qx[jp], yax, arg);                                         \
        arg = fma2(qy[jp], yay, arg);                                         \
        arg = fma2(qz[jp], yaz, arg);                                         \
        f2 s = max2(arg, clamp2);                                             \
        f2 wgt = (f2){                                                        \
            __builtin_bit_cast(float,                                         \
                (__builtin_bit_cast(int, s.x) << 15) + KBITS),                \
            __builtin_bit_cast(float,                                         \
                (__builtin_bit_cast(int, s.y) << 15) + KBITS)};               \
        acc.v2[0*QP+jp] = fma2(wgt, fax, acc.v2[0*QP+jp]);                    \
        acc.v2[1*QP+jp] = fma2(wgt, fay, acc.v2[1*QP+jp]);                    \
        acc.v2[2*QP+jp] = fma2(wgt, faz, acc.v2[2*QP+jp]);                    \
        acc.v2[3*QP+jp] = acc.v2[3*QP+jp] + wgt;                              \
    }                                                                         \
} while (0)

    // ---- stream 2048 sources from L2, 2-deep prefetch ----
    int idx = b * N1S + w * CHUNK + l;
    float4 y0 = ya[idx],      y1 = ya[idx + 64];
    uint2  f0 = fb[idx],      f1 = fb[idx + 64];
#pragma unroll 2
    for (int it = 0; it < ITERS; ++it) {
        float4 yn; uint2 fn;
        const bool more = (it + 2) < ITERS;
        if (more) { yn = ya[idx + 128]; fn = fb[idx + 128]; }
        BODY(y0, f0);
        y0 = y1; f0 = f1;
        if (more) { y1 = yn; f1 = fn; }
        idx += 64;
    }
#undef BODY

    // ---- split-exchange butterfly: 32 values, offsets 1..16 ----
#pragma unroll
    for (int step = 0; step < 5; ++step) {
        const int off  = 1 << step;
        const int half = 16 >> step;
        const bool hi  = (l & off) != 0;
#pragma unroll
        for (int k = 0; k < half; ++k) {
            float give = hi ? acc.v1[k] : acc.v1[k + half];
            float recv = __shfl_xor(give, off, 64);
            float keep = hi ? acc.v1[k + half] : acc.v1[k];
            acc.v1[k] = keep + recv;
        }
    }
    acc.v1[0] += __shfl_xor(acc.v1[0], 32, 64);  // merge the two 32-lane halves
    if (l < 32) red[w * 32 + (__brev((unsigned)l) >> 27)] = acc.v1[0];
    __syncthreads();

    // ---- combine 4 chunk partials per query, normalize, write ----
    if (t < QB) {
        int q = t;
        // flat value index for component c of query q: 2*(c*QP + q/2) + (q&1)
        float nx = 0.f, ny = 0.f, nz = 0.f, dn = 0.f;
#pragma unroll
        for (int ww = 0; ww < 4; ++ww) {
            const float* r = red + ww * 32;
            nx += r[2*(0*QP + (q>>1)) + (q&1)];
            ny += r[2*(1*QP + (q>>1)) + (q&1)];
            nz += r[2*(2*QP + (q>>1)) + (q&1)];
            dn += r[2*(3*QP + (q>>1)) + (q&1)];
        }
        float inv = 1.0f / dn;
        int n = nbase + q;
        out[b*3*N2S + 0*N2S + n] = x2b[0*N2S+n] - nx*inv;
        out[b*3*N2S + 1*N2S + n] = x2b[1*N2S+n] - ny*inv;
        out[b*3*N2S + 2*N2S + n] = x2b[2*N2S+n] - nz*inv;
    }
}

extern "C" void kernel_launch(void* const* d_in, const int* in_sizes, int n_in,
                              void* d_out, int out_size, void* d_ws, size_t ws_size,
                              hipStream_t stream) {
    const float* xyz1  = (const float*)d_in[0];
    const float* xyz2  = (const float*)d_in[1];
    const float* flow1 = (const float*)d_in[2];
    const void*  resol = d_in[3];
    float* out = (float*)d_out;

    float4* ya = (float4*)d_ws;            // NS float4 = 256 KB
    uint2*  fbp = (uint2*)(ya + NS);       // NS uint2  = 128 KB

    pw2_pack<<<NS / 256, 256, 0, stream>>>(xyz1, flow1, resol, ya, fbp);
    pw2_main<<<NQ / QB, BLK, 0, stream>>>(ya, fbp, xyz2, resol, out);
}

// Round 11
// 90.836 us; speedup vs baseline: 1.0684x; 1.0109x over previous
//
#include <hip/hip_runtime.h>

// PointWarping2: Nadaraya-Watson regression of flow1 (at warped sources
// y = xyz1+flow1) onto queries xyz2. B=2,C=3,N1=N2=8192 fp32.
//
// R11 = R10 + branch-free depth-4 software pipeline.
// R10 post-mortem: main ~39us but VALU-issue model ~11us and L2 traffic only
// 10 of 34.5 TB/s -> neither issue- nor BW-bound; the limiter is ~200cyc L2
// load latency vs ~106cyc/iter lookahead (depth-1 prefetch) at 3-4 waves/SIMD.
// Fix: 4 load-pairs in flight per wave (424cyc lookahead > 200cyc latency),
// guard-padded source arrays so tail prefetches need no branches.
// Kept (all verified): f2 packed fp32 pk math, Schraudolph exp2 with magic
// folded into packed yc (absmax 0.0586 < 0.0862), bf16-packed flow (24B/src),
// QB=8 wave-uniform SGPR query consts, split-exchange butterfly reduction.

#define N1S  8192
#define N2S  8192
#define BATCH 2
#define NS   (BATCH * N1S)     // 16384 sources
#define NQ   (BATCH * N2S)     // 16384 queries
#define GUARD 256              // guard elements for unconditional prefetch
#define BLK  256               // 4 waves
#define QB   8                 // queries per block (shared by all 4 waves)
#define QP   4                 // f2 query-pairs per wave
#define CHUNK 2048             // sources per wave
#define ITERS (CHUNK / 64)     // 32
#define DEPTH 4                // software-pipeline depth
#define LOG2E 1.4426950408889634f
#define MAGIC 49152.0f         // 1.5*2^15
#define CLAMPS (MAGIC - 120.0f)
#define KBITS 1064990910       // (127<<23) - 362306: rel err +-3.04%

typedef float f2 __attribute__((ext_vector_type(2)));

__device__ __forceinline__ f2 fma2(f2 a, f2 b, f2 c) {
    return __builtin_elementwise_fma(a, b, c);
}
__device__ __forceinline__ f2 max2(f2 a, f2 b) {
    return __builtin_elementwise_max(a, b);
}

__device__ __forceinline__ float rfl(float x) {   // force wave-uniform -> SGPR
    return __builtin_bit_cast(float,
        __builtin_amdgcn_readfirstlane(__builtin_bit_cast(int, x)));
}

__device__ __forceinline__ float read_scale(const void* p) {
    // resol_factor: 1-elem array; Python int -> int32, float -> fp32.
    int iv = *(const int*)p;
    if (iv > -(1 << 23) && iv < (1 << 23)) return (float)iv;
    return *(const float*)p;
}

__device__ __forceinline__ unsigned bf16_rne(float v) {   // round-nearest-even
    unsigned u = __builtin_bit_cast(unsigned, v);
    return (u + 0x7FFFu + ((u >> 16) & 1u)) >> 16;
}

// ---- k1: ya[i]={yx,yy,yz, MAGIC-c1|y|^2}, fb[i]={bf16 fy:fx, bf16 0:fz} ----
__global__ __launch_bounds__(256) void pw2_pack(
    const float* __restrict__ xyz1, const float* __restrict__ flow1,
    const void* __restrict__ resol, float4* __restrict__ ya,
    uint2* __restrict__ fb)
{
    int i = blockIdx.x * 256 + threadIdx.x;
    if (i >= NS) return;
    int b = i >> 13, m = i & (N1S - 1);
    const float scale = read_scale(resol);
    const float c1 = LOG2E / (scale * scale);
    const float* x1b = xyz1  + b * 3 * N1S;
    const float* f1b = flow1 + b * 3 * N1S;
    float fx = f1b[0*N1S+m], fy = f1b[1*N1S+m], fz = f1b[2*N1S+m];
    float yx = x1b[0*N1S+m]+fx, yy = x1b[1*N1S+m]+fy, yz = x1b[2*N1S+m]+fz;
    float yc = MAGIC - c1 * (yx*yx + yy*yy + yz*yz);
    ya[i] = make_float4(yx, yy, yz, yc);
    fb[i] = make_uint2((bf16_rne(fy) << 16) | bf16_rne(fx), bf16_rne(fz));
}

// ---- k2: main streaming kernel ----
__global__ __launch_bounds__(BLK) void pw2_main(
    const float4* __restrict__ ya, const uint2* __restrict__ fb,
    const float* __restrict__ xyz2, const void* __restrict__ resol,
    float* __restrict__ out)
{
    __shared__ float red[4 * 32];      // [wave][32 reduced values]

    const int t = threadIdx.x;
    const int w = t >> 6;              // wave = source chunk
    const int l = t & 63;

    const int qblk  = blockIdx.x * QB;
    const int b     = qblk >> 13;
    const int nbase = qblk & (N2S - 1);

    const float scale = read_scale(resol);   // INITIAL_RADIUS == 1.0
    const float c1    = LOG2E / (scale * scale);
    const float twoC  = 2.0f * c1;

    const float* x2b = xyz2 + b * 3 * N2S;

    // ---- wave-uniform query constants (8 queries, f2 pairs) -> SGPRs ----
    f2 qx[QP], qy[QP], qz[QP], qc[QP];
#pragma unroll
    for (int jp = 0; jp < QP; ++jp) {
        int n0 = nbase + 2 * jp;
        float x0 = x2b[0*N2S+n0],   y0 = x2b[1*N2S+n0],   z0 = x2b[2*N2S+n0];
        float x1 = x2b[0*N2S+n0+1], y1 = x2b[1*N2S+n0+1], z1 = x2b[2*N2S+n0+1];
        qc[jp] = (f2){rfl(-c1 * (x0*x0 + y0*y0 + z0*z0)),
                      rfl(-c1 * (x1*x1 + y1*y1 + z1*z1))};
        qx[jp] = (f2){rfl(twoC*x0), rfl(twoC*x1)};
        qy[jp] = (f2){rfl(twoC*y0), rfl(twoC*y1)};
        qz[jp] = (f2){rfl(twoC*z0), rfl(twoC*z1)};
    }
    const f2 clamp2 = (f2){CLAMPS, CLAMPS};

    // acc.v2[c*QP+jp]: c=0/1/2 numerator xyz, c=3 denominator; 32 floats
    union Acc { f2 v2[16]; float v1[32]; } acc;
#pragma unroll
    for (int i = 0; i < 16; ++i) acc.v2[i] = (f2){0.f, 0.f};

#define BODY(Y4, FU) do {                                                     \
    f2 yaw = (f2){(Y4).w, (Y4).w};                                            \
    f2 yax = (f2){(Y4).x, (Y4).x};                                            \
    f2 yay = (f2){(Y4).y, (Y4).y};                                            \
    f2 yaz = (f2){(Y4).z, (Y4).z};                                            \
    float ffx = __builtin_bit_cast(float, (FU).x << 16);                      \
    float ffy = __builtin_bit_cast(float, (FU).x & 0xFFFF0000u);              \
    float ffz = __builtin_bit_cast(float, (FU).y << 16);                      \
    f2 fax = (f2){ffx, ffx}, fay = (f2){ffy, ffy}, faz = (f2){ffz, ffz};      \
    _Pragma("unroll")                                                         \
    for (int jp = 0; jp < QP; ++jp) {                                         \
        f2 arg = qc[jp] + yaw;                                                \
        arg = fma2(qx[jp], yax, arg);                                         \
        arg = fma2(qy[jp], yay, arg);                                         \
        arg = fma2(qz[jp], yaz, arg);                                         \
        f2 s = max2(arg, clamp2);                                             \
        f2 wgt = (f2){                                                        \
            __builtin_bit_cast(float,                                         \
                (__builtin_bit_cast(int, s.x) << 15) + KBITS),                \
            __builtin_bit_cast(float,                                         \
                (__builtin_bit_cast(int, s.y) << 15) + KBITS)};               \
        acc.v2[0*QP+jp] = fma2(wgt, fax, acc.v2[0*QP+jp]);                    \
        acc.v2[1*QP+jp] = fma2(wgt, fay, acc.v2[1*QP+jp]);                    \
        acc.v2[2*QP+jp] = fma2(wgt, faz, acc.v2[2*QP+jp]);                    \
        acc.v2[3*QP+jp] = acc.v2[3*QP+jp] + wgt;                              \
    }                                                                         \
} while (0)

    // ---- depth-4 branch-free pipeline over 2048 sources (guarded tail) ----
    int idx = b * N1S + w * CHUNK + l;
    float4 yb[DEPTH]; uint2 fu[DEPTH];
#pragma unroll
    for (int p = 0; p < DEPTH; ++p) {
        yb[p] = ya[idx + p * 64];
        fu[p] = fb[idx + p * 64];
    }
#pragma unroll 4
    for (int it = 0; it < ITERS; ++it) {
        // prefetch it+DEPTH (guard padding makes the tail reads legal)
        float4 yn = ya[idx + DEPTH * 64];
        uint2  fn = fb[idx + DEPTH * 64];
        BODY(yb[it & (DEPTH - 1)], fu[it & (DEPTH - 1)]);
        yb[it & (DEPTH - 1)] = yn;
        fu[it & (DEPTH - 1)] = fn;
        idx += 64;
    }
#undef BODY

    // ---- split-exchange butterfly: 32 values, offsets 1..16 ----
#pragma unroll
    for (int step = 0; step < 5; ++step) {
        const int off  = 1 << step;
        const int half = 16 >> step;
        const bool hi  = (l & off) != 0;
#pragma unroll
        for (int k = 0; k < half; ++k) {
            float give = hi ? acc.v1[k] : acc.v1[k + half];
            float recv = __shfl_xor(give, off, 64);
            float keep = hi ? acc.v1[k + half] : acc.v1[k];
            acc.v1[k] = keep + recv;
        }
    }
    acc.v1[0] += __shfl_xor(acc.v1[0], 32, 64);  // merge the two 32-lane halves
    if (l < 32) red[w * 32 + (__brev((unsigned)l) >> 27)] = acc.v1[0];
    __syncthreads();

    // ---- combine 4 chunk partials per query, normalize, write ----
    if (t < QB) {
        int q = t;
        // flat value index for component c of query q: 2*(c*QP + q/2) + (q&1)
        float nx = 0.f, ny = 0.f, nz = 0.f, dn = 0.f;
#pragma unroll
        for (int ww = 0; ww < 4; ++ww) {
            const float* r = red + ww * 32;
            nx += r[2*(0*QP + (q>>1)) + (q&1)];
            ny += r[2*(1*QP + (q>>1)) + (q&1)];
            nz += r[2*(2*QP + (q>>1)) + (q&1)];
            dn += r[2*(3*QP + (q>>1)) + (q&1)];
        }
        float inv = 1.0f / dn;
        int n = nbase + q;
        out[b*3*N2S + 0*N2S + n] = x2b[0*N2S+n] - nx*inv;
        out[b*3*N2S + 1*N2S + n] = x2b[1*N2S+n] - ny*inv;
        out[b*3*N2S + 2*N2S + n] = x2b[2*N2S+n] - nz*inv;
    }
}

extern "C" void kernel_launch(void* const* d_in, const int* in_sizes, int n_in,
                              void* d_out, int out_size, void* d_ws, size_t ws_size,
                              hipStream_t stream) {
    const float* xyz1  = (const float*)d_in[0];
    const float* xyz2  = (const float*)d_in[1];
    const float* flow1 = (const float*)d_in[2];
    const void*  resol = d_in[3];
    float* out = (float*)d_out;

    float4* ya = (float4*)d_ws;                 // (NS+GUARD) float4
    uint2*  fbp = (uint2*)(ya + NS + GUARD);    // (NS+GUARD) uint2

    pw2_pack<<<NS / 256, 256, 0, stream>>>(xyz1, flow1, resol, ya, fbp);
    pw2_main<<<NQ / QB, BLK, 0, stream>>>(ya, fbp, xyz2, resol, out);
}

// Round 12
// 88.848 us; speedup vs baseline: 1.0923x; 1.0224x over previous
//
#include <hip/hip_runtime.h>

// PointWarping2: Nadaraya-Watson regression of flow1 (at warped sources
// y = xyz1+flow1) onto queries xyz2. B=2,C=3,N1=N2=8192 fp32.
//
// R12: one 16B record per source -> single dwordx4 load stream.
//   u.x = half(yy)<<16 | half(yx)        (fp16: rel err 5e-4 -> arg err ~0.9%)
//   u.y = bf16(fx)<<16 | half(yz)
//   u.z = bf16(fz)<<16 | bf16(fy)        (flow ~0.1 scale; bf16 err ~4e-4 abs)
//   u.w = fp32 (MAGIC - c1*|y|^2)        (magic-folded Schraudolph term)
// R7-R11 evidence: kernel is L2-delivery-bound (~10.4 TB/s effective, not
// VALU: killing v_exp bought ~nothing). -33% bytes + half the loads + depth-6
// pipeline attacks exactly that. Kept: f2 pk math, Schraudolph exp2
// (absmax 0.0586 prior), QB=8 SGPR query consts, split-exchange butterfly.

#define N1S  8192
#define N2S  8192
#define BATCH 2
#define NS   (BATCH * N1S)     // 16384 sources
#define NQ   (BATCH * N2S)     // 16384 queries
#define GUARD 512              // guard elements for unconditional prefetch
#define BLK  256               // 4 waves
#define QB   8                 // queries per block (shared by all 4 waves)
#define QP   4                 // f2 query-pairs per wave
#define CHUNK 2048             // sources per wave
#define ITERS (CHUNK / 64)     // 32
#define DEPTH 6                // software-pipeline depth (~600 cyc lookahead)
#define LOG2E 1.4426950408889634f
#define MAGIC 49152.0f         // 1.5*2^15
#define CLAMPS (MAGIC - 120.0f)
#define KBITS 1064990910       // (127<<23) - 362306: rel err +-3.04%

typedef float f2 __attribute__((ext_vector_type(2)));

__device__ __forceinline__ f2 fma2(f2 a, f2 b, f2 c) {
    return __builtin_elementwise_fma(a, b, c);
}
__device__ __forceinline__ f2 max2(f2 a, f2 b) {
    return __builtin_elementwise_max(a, b);
}

__device__ __forceinline__ float rfl(float x) {   // force wave-uniform -> SGPR
    return __builtin_bit_cast(float,
        __builtin_amdgcn_readfirstlane(__builtin_bit_cast(int, x)));
}

__device__ __forceinline__ float read_scale(const void* p) {
    // resol_factor: 1-elem array; Python int -> int32, float -> fp32.
    int iv = *(const int*)p;
    if (iv > -(1 << 23) && iv < (1 << 23)) return (float)iv;
    return *(const float*)p;
}

__device__ __forceinline__ unsigned bf16_rne(float v) {   // round-nearest-even
    unsigned u = __builtin_bit_cast(unsigned, v);
    return (u + 0x7FFFu + ((u >> 16) & 1u)) >> 16;
}

__device__ __forceinline__ unsigned h16(float v) {        // fp16 bits
    return (unsigned)__builtin_bit_cast(unsigned short, (_Float16)v);
}

__device__ __forceinline__ float h2f(unsigned bits16) {   // fp16 bits -> fp32
    return (float)__builtin_bit_cast(_Float16, (unsigned short)bits16);
}

// ---- k1: pack one uint4 record per source ----
__global__ __launch_bounds__(256) void pw2_pack(
    const float* __restrict__ xyz1, const float* __restrict__ flow1,
    const void* __restrict__ resol, uint4* __restrict__ src)
{
    int i = blockIdx.x * 256 + threadIdx.x;
    if (i >= NS) return;
    int b = i >> 13, m = i & (N1S - 1);
    const float scale = read_scale(resol);
    const float c1 = LOG2E / (scale * scale);
    const float* x1b = xyz1  + b * 3 * N1S;
    const float* f1b = flow1 + b * 3 * N1S;
    float fx = f1b[0*N1S+m], fy = f1b[1*N1S+m], fz = f1b[2*N1S+m];
    float yx = x1b[0*N1S+m]+fx, yy = x1b[1*N1S+m]+fy, yz = x1b[2*N1S+m]+fz;
    float yc = MAGIC - c1 * (yx*yx + yy*yy + yz*yz);  // fp32: exact fold
    uint4 u;
    u.x = (h16(yy) << 16) | h16(yx);
    u.y = (bf16_rne(fx) << 16) | h16(yz);
    u.z = (bf16_rne(fz) << 16) | bf16_rne(fy);
    u.w = __builtin_bit_cast(unsigned, yc);
    src[i] = u;
}

// ---- k2: main streaming kernel ----
__global__ __launch_bounds__(BLK) void pw2_main(
    const uint4* __restrict__ src, const float* __restrict__ xyz2,
    const void* __restrict__ resol, float* __restrict__ out)
{
    __shared__ float red[4 * 32];      // [wave][32 reduced values]

    const int t = threadIdx.x;
    const int w = t >> 6;              // wave = source chunk
    const int l = t & 63;

    const int qblk  = blockIdx.x * QB;
    const int b     = qblk >> 13;
    const int nbase = qblk & (N2S - 1);

    const float scale = read_scale(resol);   // INITIAL_RADIUS == 1.0
    const float c1    = LOG2E / (scale * scale);
    const float twoC  = 2.0f * c1;

    const float* x2b = xyz2 + b * 3 * N2S;

    // ---- wave-uniform query constants (8 queries, f2 pairs) -> SGPRs ----
    f2 qx[QP], qy[QP], qz[QP], qc[QP];
#pragma unroll
    for (int jp = 0; jp < QP; ++jp) {
        int n0 = nbase + 2 * jp;
        float x0 = x2b[0*N2S+n0],   y0 = x2b[1*N2S+n0],   z0 = x2b[2*N2S+n0];
        float x1 = x2b[0*N2S+n0+1], y1 = x2b[1*N2S+n0+1], z1 = x2b[2*N2S+n0+1];
        qc[jp] = (f2){rfl(-c1 * (x0*x0 + y0*y0 + z0*z0)),
                      rfl(-c1 * (x1*x1 + y1*y1 + z1*z1))};
        qx[jp] = (f2){rfl(twoC*x0), rfl(twoC*x1)};
        qy[jp] = (f2){rfl(twoC*y0), rfl(twoC*y1)};
        qz[jp] = (f2){rfl(twoC*z0), rfl(twoC*z1)};
    }
    const f2 clamp2 = (f2){CLAMPS, CLAMPS};

    // acc.v2[c*QP+jp]: c=0/1/2 numerator xyz, c=3 denominator; 32 floats
    union Acc { f2 v2[16]; float v1[32]; } acc;
#pragma unroll
    for (int i = 0; i < 16; ++i) acc.v2[i] = (f2){0.f, 0.f};

#define BODY(U) do {                                                          \
    float vyx = h2f((U).x & 0xFFFFu);                                         \
    float vyy = h2f((U).x >> 16);                                             \
    float vyz = h2f((U).y & 0xFFFFu);                                         \
    float ffx = __builtin_bit_cast(float, (U).y & 0xFFFF0000u);               \
    float ffy = __builtin_bit_cast(float, (U).z << 16);                       \
    float ffz = __builtin_bit_cast(float, (U).z & 0xFFFF0000u);               \
    float vyc = __builtin_bit_cast(float, (U).w);                             \
    f2 yaw = (f2){vyc, vyc};                                                  \
    f2 yax = (f2){vyx, vyx}, yay = (f2){vyy, vyy}, yaz = (f2){vyz, vyz};      \
    f2 fax = (f2){ffx, ffx}, fay = (f2){ffy, ffy}, faz = (f2){ffz, ffz};      \
    _Pragma("unroll")                                                         \
    for (int jp = 0; jp < QP; ++jp) {                                         \
        f2 arg = qc[jp] + yaw;                                                \
        arg = fma2(qx[jp], yax, arg);                                         \
        arg = fma2(qy[jp], yay, arg);                                         \
        arg = fma2(qz[jp], yaz, arg);                                         \
        f2 s = max2(arg, clamp2);                                             \
        f2 wgt = (f2){                                                        \
            __builtin_bit_cast(float,                                         \
                (__builtin_bit_cast(int, s.x) << 15) + KBITS),                \
            __builtin_bit_cast(float,                                         \
                (__builtin_bit_cast(int, s.y) << 15) + KBITS)};               \
        acc.v2[0*QP+jp] = fma2(wgt, fax, acc.v2[0*QP+jp]);                    \
        acc.v2[1*QP+jp] = fma2(wgt, fay, acc.v2[1*QP+jp]);                    \
        acc.v2[2*QP+jp] = fma2(wgt, faz, acc.v2[2*QP+jp]);                    \
        acc.v2[3*QP+jp] = acc.v2[3*QP+jp] + wgt;                              \
    }                                                                         \
} while (0)

    // ---- depth-6 branch-free pipeline over 2048 sources (guarded tail) ----
    int idx = b * N1S + w * CHUNK + l;
    uint4 ub[DEPTH];
#pragma unroll
    for (int p = 0; p < DEPTH; ++p) ub[p] = src[idx + p * 64];
#pragma unroll 6
    for (int it = 0; it < ITERS; ++it) {
        uint4 un = src[idx + DEPTH * 64];   // guard padding: always legal
        BODY(ub[it % DEPTH]);
        ub[it % DEPTH] = un;
        idx += 64;
    }
#undef BODY

    // ---- split-exchange butterfly: 32 values, offsets 1..16 ----
#pragma unroll
    for (int step = 0; step < 5; ++step) {
        const int off  = 1 << step;
        const int half = 16 >> step;
        const bool hi  = (l & off) != 0;
#pragma unroll
        for (int k = 0; k < half; ++k) {
            float give = hi ? acc.v1[k] : acc.v1[k + half];
            float recv = __shfl_xor(give, off, 64);
            float keep = hi ? acc.v1[k + half] : acc.v1[k];
            acc.v1[k] = keep + recv;
        }
    }
    acc.v1[0] += __shfl_xor(acc.v1[0], 32, 64);  // merge the two 32-lane halves
    if (l < 32) red[w * 32 + (__brev((unsigned)l) >> 27)] = acc.v1[0];
    __syncthreads();

    // ---- combine 4 chunk partials per query, normalize, write ----
    if (t < QB) {
        int q = t;
        // flat value index for component c of query q: 2*(c*QP + q/2) + (q&1)
        float nx = 0.f, ny = 0.f, nz = 0.f, dn = 0.f;
#pragma unroll
        for (int ww = 0; ww < 4; ++ww) {
            const float* r = red + ww * 32;
            nx += r[2*(0*QP + (q>>1)) + (q&1)];
            ny += r[2*(1*QP + (q>>1)) + (q&1)];
            nz += r[2*(2*QP + (q>>1)) + (q&1)];
            dn += r[2*(3*QP + (q>>1)) + (q&1)];
        }
        float inv = 1.0f / dn;
        int n = nbase + q;
        out[b*3*N2S + 0*N2S + n] = x2b[0*N2S+n] - nx*inv;
        out[b*3*N2S + 1*N2S + n] = x2b[1*N2S+n] - ny*inv;
        out[b*3*N2S + 2*N2S + n] = x2b[2*N2S+n] - nz*inv;
    }
}

extern "C" void kernel_launch(void* const* d_in, const int* in_sizes, int n_in,
                              void* d_out, int out_size, void* d_ws, size_t ws_size,
                              hipStream_t stream) {
    const float* xyz1  = (const float*)d_in[0];
    const float* xyz2  = (const float*)d_in[1];
    const float* flow1 = (const float*)d_in[2];
    const void*  resol = d_in[3];
    float* out = (float*)d_out;

    uint4* src = (uint4*)d_ws;             // (NS+GUARD) uint4 = ~270 KB

    pw2_pack<<<NS / 256, 256, 0, stream>>>(xyz1, flow1, resol, src);
    pw2_main<<<NQ / QB, BLK, 0, stream>>>(src, xyz2, resol, out);
}